// Round 8
// baseline (3473.431 us; speedup 1.0000x reference)
//
#include <hip/hip_runtime.h>
#include <stdint.h>

// LSTM B=256,T=1024,I=64,H=256,O=1. fp32 in/out, bf16 MFMA internally.
//
// Round-8: WAVE-SPECIALIZED exchange. Evidence: R3 (tag-in-data spam poll)
// 2.30us/step; R7 (flag poll + separate bulk load) 2.77us/step — the +0.47us
// is exactly one extra MALL trip => data must ride WITH detection. The
// remaining serialization is that the SAME waves poll and compute. Now each
// 384-thread block = 4 compute waves + 2 POLLER waves. While compute does
// h-MFMA/update/store for step t, pollers concurrently sweep the tagged
// units of step t+1 (8B {2xbf16,tag} units, sc0 sc1 = MALL-coherent, proven
// R1-R4) and deposit h into LDS. One __syncthreads per step hands off.
// Critical path/step ~= compute(~600cy) + residual detect(~1100cy) overlap.
//
// Skew safety: block A can store tag t+1 only after detecting tag t, which
// needs every peer's tag-t store, which follows that peer's successful
// tag-(t-1) sweep => max skew 1 step; a parity buffer polled for tag v is
// only ever overwritten with v (monotonic), so mixed sweeps self-resolve.
// Pollers poll for the NEW value -> no deadlock. Payload+tag captured in the
// same sweep (atomic 8B units). Poison 0xAAAAAAAA never equals live tags
// 1..1024 => no ws init. Dead-latch cap => wrong-answer-not-hang.
//
// 128 blocks = 16 batch-groups (16 batches) x 8 gate-slices. Compute waves
// keep round-7's VERIFIED operand-swapped MFMA (A=W, B=h ->
// C[gate_row][batch]), in-wave gate transpose, and update.

#define T_ 1024
#define I_ 64
#define H_ 256
#define NGROUP 16
#define NSLICE 8
#define NBLK (NGROUP * NSLICE) /* 128 */
#define NTHR 384               /* 4 compute + 2 poller waves */
#define UPG 2048               /* 8B units per group per parity */
#define UPALL (NGROUP * UPG)
#define POLL_CAP (1 << 17)

typedef float floatx4 __attribute__((ext_vector_type(4)));
typedef __bf16 bf16x8 __attribute__((ext_vector_type(8)));
typedef unsigned short ushortx8 __attribute__((ext_vector_type(8)));
typedef unsigned int uintx4 __attribute__((ext_vector_type(4)));
typedef unsigned int uint32;
typedef unsigned long long u64;
typedef unsigned short ushort;

__device__ __forceinline__ ushort f2bf(float f) {
  uint32 u = __builtin_bit_cast(uint32, f);
  u = (u + 0x7FFFu + ((u >> 16) & 1u)) >> 16;  // RNE
  return (ushort)u;
}
__device__ __forceinline__ uint32 pack2bf(float a, float b) {
  return (uint32)f2bf(a) | ((uint32)f2bf(b) << 16);
}
__device__ __forceinline__ bf16x8 packbf8(floatx4 a, floatx4 b) {
  bf16x8 r;
  r[0] = (__bf16)a[0]; r[1] = (__bf16)a[1];
  r[2] = (__bf16)a[2]; r[3] = (__bf16)a[3];
  r[4] = (__bf16)b[0]; r[5] = (__bf16)b[1];
  r[6] = (__bf16)b[2]; r[7] = (__bf16)b[3];
  return r;
}
__device__ __forceinline__ float fast_sig(float v) {
  return 1.0f / (1.0f + __expf(-v));
}
__device__ __forceinline__ float fast_tanh(float v) {
  float e = __expf(2.0f * v);
  return 1.0f - 2.0f / (e + 1.0f);
}
__device__ __forceinline__ void astore64(u64* p, u64 v) {
  __hip_atomic_store(p, v, __ATOMIC_RELAXED, __HIP_MEMORY_SCOPE_AGENT);
}

// Load 8 tagged units (64B) MALL-coherently; tags in odd dwords must == t.
// Early-clobber outputs: must not alias the address pair %4.
__device__ __forceinline__ bool load8_check(const u64* up, int t, uintx4& a0,
                                            uintx4& a1, uintx4& a2,
                                            uintx4& a3) {
  asm volatile(
      "global_load_dwordx4 %0, %4, off sc0 sc1\n\t"
      "global_load_dwordx4 %1, %4, off offset:16 sc0 sc1\n\t"
      "global_load_dwordx4 %2, %4, off offset:32 sc0 sc1\n\t"
      "global_load_dwordx4 %3, %4, off offset:48 sc0 sc1\n\t"
      "s_waitcnt vmcnt(0)"
      : "=&v"(a0), "=&v"(a1), "=&v"(a2), "=&v"(a3)
      : "v"(up)
      : "memory");
  return ((int)a0[1] == t) & ((int)a0[3] == t) & ((int)a1[1] == t) &
         ((int)a1[3] == t) & ((int)a2[1] == t) & ((int)a2[3] == t) &
         ((int)a3[1] == t) & ((int)a3[3] == t);
}

__global__ __launch_bounds__(NTHR, 1) void lstm_main(
    const float* __restrict__ x, const float* __restrict__ W_ih,
    const float* __restrict__ W_hh, const float* __restrict__ b_ih,
    const float* __restrict__ b_hh, const float* __restrict__ fc_w,
    float* __restrict__ partials, u64* __restrict__ units) {
  const int tid = threadIdx.x;
  const int bid = blockIdx.x;
  const int g = bid >> 3;   // batch-group 0..15
  const int sl = bid & 7;   // gate-slice 0..7
  const int w = tid >> 6;   // wave: 0..3 compute, 4..5 poller
  const int lane = tid & 63;
  const int ln = lane & 15;
  const int q = lane >> 4;

  // h_lds rows are 272 ushorts (544B = 34x16B): 16B-aligned rows for b128.
  __shared__ __align__(16) ushort h_lds[2][16][272];
  __shared__ float tsc[4][16 * 36];  // per-compute-wave gate transpose
  __shared__ float fcred[4][16];

  // zero both h parity buffers (t=0 reads parity 0 as h=0)
  {
    uint32* p = (uint32*)&h_lds[0][0][0];
    for (int i = tid; i < 2 * 16 * 136; i += NTHR) p[i] = 0u;
  }

  // =============== compute-wave setup (w<4) ===============
  bf16x8 whh[2][8], wih[2][2];
  floatx4 biasv[2];
  float fcw0 = 0.f, fcw1 = 0.f;
  const float* xb = nullptr;
  u64* ust = nullptr;
  floatx4 xp0, xp1, xp2, xp3;
  if (w < 4) {
    const int gate = ln >> 2, hid = ln & 3;
#pragma unroll
    for (int tau = 0; tau < 2; ++tau) {
      const int row = gate * 256 + sl * 32 + w * 8 + tau * 4 + hid;
#pragma unroll
      for (int kc = 0; kc < 8; ++kc) {
        const float* p = W_hh + (size_t)row * H_ + kc * 32 + q * 8;
        whh[tau][kc] = packbf8(*(const floatx4*)p, *(const floatx4*)(p + 4));
      }
#pragma unroll
      for (int kc = 0; kc < 2; ++kc) {
        const float* p = W_ih + (size_t)row * I_ + kc * 32 + q * 8;
        wih[tau][kc] = packbf8(*(const floatx4*)p, *(const floatx4*)(p + 4));
      }
#pragma unroll
      for (int j = 0; j < 4; ++j) {
        const int br = q * 256 + sl * 32 + w * 8 + tau * 4 + j;
        biasv[tau][j] = b_ih[br] + b_hh[br];
      }
    }
    const int u0 = sl * 32 + w * 8 + 2 * q;
    fcw0 = fc_w[u0];
    fcw1 = fc_w[u0 + 1];
    xb = x + (size_t)(g * 16 + ln) * T_ * I_;
    ust = units + (size_t)g * UPG + ((sl * 16 + w * 4 + q) * 16 + ln);
    const float* xs = xb + q * 8;
    xp0 = *(const floatx4*)xs;
    xp1 = *(const floatx4*)(xs + 4);
    xp2 = *(const floatx4*)(xs + 32);
    xp3 = *(const floatx4*)(xs + 36);
  }
  // =============== poller-wave setup (w>=4) ===============
  const int pw = w - 4;                 // 0..1
  const int hp = pw * 64 + lane;        // hidden-pair 0..127 this lane owns
  const u64* pbase = units + (size_t)g * UPG + (size_t)hp * 16;
  bool dead = false;

  float c0 = 0.0f, c1 = 0.0f, partial = 0.0f;

#pragma unroll 1
  for (int t = 0; t < T_; ++t) {
    floatx4 acc0, acc1;
    if (w < 4) {  // x-part MFMAs before the barrier (independent of h)
      bf16x8 bx0 = packbf8(xp0, xp1);
      bf16x8 bx1 = packbf8(xp2, xp3);
      acc0 = biasv[0];
      acc1 = biasv[1];
      acc0 = __builtin_amdgcn_mfma_f32_16x16x32_bf16(wih[0][0], bx0, acc0, 0, 0, 0);
      acc0 = __builtin_amdgcn_mfma_f32_16x16x32_bf16(wih[0][1], bx1, acc0, 0, 0, 0);
      acc1 = __builtin_amdgcn_mfma_f32_16x16x32_bf16(wih[1][0], bx0, acc1, 0, 0, 0);
      acc1 = __builtin_amdgcn_mfma_f32_16x16x32_bf16(wih[1][1], bx1, acc1, 0, 0, 0);
    }
    __syncthreads();  // h_lds[t&1] ready (pollers wrote it last iteration)

    if (w < 4) {
      // ---- h-part MFMAs (t=0: h_lds[0] is zero) ----
      const ushort* hr = &h_lds[t & 1][ln][0];
#pragma unroll
      for (int kc = 0; kc < 8; ++kc) {
        bf16x8 hf = __builtin_bit_cast(
            bf16x8, *(const ushortx8*)(hr + kc * 32 + q * 8));
        acc0 = __builtin_amdgcn_mfma_f32_16x16x32_bf16(whh[0][kc], hf, acc0, 0, 0, 0);
        acc1 = __builtin_amdgcn_mfma_f32_16x16x32_bf16(whh[1][kc], hf, acc1, 0, 0, 0);
      }
      // ---- in-wave 4x8 gate transpose (round-7 verified) ----
      {
        float* tb = &tsc[w][ln * 36];
        tb[0 + q] = acc0[0];  tb[4 + q] = acc0[1];
        tb[8 + q] = acc0[2];  tb[12 + q] = acc0[3];
        tb[16 + q] = acc1[0]; tb[20 + q] = acc1[1];
        tb[24 + q] = acc1[2]; tb[28 + q] = acc1[3];
      }
      floatx4 pe = *(const floatx4*)&tsc[w][ln * 36 + 8 * q];
      floatx4 po = *(const floatx4*)&tsc[w][ln * 36 + 8 * q + 4];
      // ---- update: lane owns (hidden u0,u0+1) x batch ln ----
      float iv = fast_sig(pe[0]), fv = fast_sig(pe[1]);
      float gv = fast_tanh(pe[2]), ov = fast_sig(pe[3]);
      c0 = fv * c0 + iv * gv;
      float h0 = ov * fast_tanh(c0);
      iv = fast_sig(po[0]); fv = fast_sig(po[1]);
      gv = fast_tanh(po[2]); ov = fast_sig(po[3]);
      c1 = fv * c1 + iv * gv;
      float h1 = ov * fast_tanh(c1);
      u64 val = (u64)pack2bf(h0, h1) | ((u64)(uint32)(t + 1) << 32);
      astore64(ust + (size_t)((t + 1) & 1) * UPALL, val);
      if (t == T_ - 1) partial = h0 * fcw0 + h1 * fcw1;
      if (t + 1 < T_) {  // prefetch x(t+1)
        const float* xs = xb + (t + 1) * I_ + q * 8;
        xp0 = *(const floatx4*)xs;
        xp1 = *(const floatx4*)(xs + 4);
        xp2 = *(const floatx4*)(xs + 32);
        xp3 = *(const floatx4*)(xs + 36);
      }
    } else if (t + 1 < T_ && !dead) {
      // ---- pollers: detect step t+1 concurrently with compute of t ----
      const int par = (t + 1) & 1;
      const int tag = t + 1;
      const u64* up = pbase + (size_t)par * UPALL;
      uintx4 a0, a1, a2, a3, b0, b1, b2, b3;
      int sweeps = 0;
      bool ok;
      do {
        bool o1 = load8_check(up, tag, a0, a1, a2, a3);
        bool o2 = load8_check(up + 8, tag, b0, b1, b2, b3);
        ok = o1 & o2;
      } while (!__all(ok) && ++sweeps < POLL_CAP);
      if (sweeps >= POLL_CAP) dead = true;  // terminate wrong, don't hang
      // deposit: unit j of this lane = batch j; dword column = hp
      uint32* hw = ((uint32*)&h_lds[par][0][0]) + hp;
      hw[0 * 136] = a0[0];  hw[1 * 136] = a0[2];
      hw[2 * 136] = a1[0];  hw[3 * 136] = a1[2];
      hw[4 * 136] = a2[0];  hw[5 * 136] = a2[2];
      hw[6 * 136] = a3[0];  hw[7 * 136] = a3[2];
      hw[8 * 136] = b0[0];  hw[9 * 136] = b0[2];
      hw[10 * 136] = b1[0]; hw[11 * 136] = b1[2];
      hw[12 * 136] = b2[0]; hw[13 * 136] = b2[2];
      hw[14 * 136] = b3[0]; hw[15 * 136] = b3[2];
    }
  }

  // ---- FC partial: reduce over q (shfl) then compute waves (LDS) ----
  if (w < 4) {
    partial += __shfl_xor(partial, 16);
    partial += __shfl_xor(partial, 32);
    if (lane < 16) fcred[w][lane] = partial;
  }
  __syncthreads();
  if (tid < 16) {
    float v = fcred[0][tid] + fcred[1][tid] + fcred[2][tid] + fcred[3][tid];
    __hip_atomic_store(&partials[(g * 8 + sl) * 16 + tid], v, __ATOMIC_RELAXED,
                       __HIP_MEMORY_SCOPE_AGENT);
  }
}

__global__ void lstm_fc(const float* __restrict__ partials,
                        const float* __restrict__ fc_b,
                        float* __restrict__ out) {
  const int tid = threadIdx.x;  // batch = g*16 + ln = tid
  const int g = tid >> 4, ln = tid & 15;
  float s = fc_b[0];
#pragma unroll
  for (int sl = 0; sl < 8; ++sl)
    s += __hip_atomic_load(&partials[(g * 8 + sl) * 16 + ln], __ATOMIC_RELAXED,
                           __HIP_MEMORY_SCOPE_AGENT);
  out[tid] = s;
}

extern "C" void kernel_launch(void* const* d_in, const int* in_sizes, int n_in,
                              void* d_out, int out_size, void* d_ws,
                              size_t ws_size, hipStream_t stream) {
  const float* x    = (const float*)d_in[0];
  const float* W_ih = (const float*)d_in[1];
  const float* W_hh = (const float*)d_in[2];
  const float* b_ih = (const float*)d_in[3];
  const float* b_hh = (const float*)d_in[4];
  const float* fc_w = (const float*)d_in[5];
  const float* fc_b = (const float*)d_in[6];
  float* out = (float*)d_out;

  // ws: [1K,9K) partials (2048 f32); [16K, 16K+512K) units
  //     (2 parities x 16 groups x 2048 x 8B). Poison needs no init.
  float* partials = (float*)((char*)d_ws + 1024);
  u64* units = (u64*)((char*)d_ws + 16384);

  lstm_main<<<dim3(NBLK), dim3(NTHR), 0, stream>>>(
      x, W_ih, W_hh, b_ih, b_hh, fc_w, partials, units);
  lstm_fc<<<dim3(1), dim3(256), 0, stream>>>(partials, fc_b, out);
}

// Round 9
// 2235.012 us; speedup vs baseline: 1.5541x; 1.5541x over previous
//
#include <hip/hip_runtime.h>
#include <stdint.h>

// LSTM: B=256, T=1024, I=64, H=256, O=1. fp32 in/out, bf16 MFMA internally.
//
// Round-9 = Round-3 (best, 2356us, verified) + QUIET two-phase polling.
// Cross-round model: base MALL RTT ~2200-2800cy; continuous uncached polling
// inflates it (R3 spam-poll eff-RTT ~4400; R8 dedicated pollers ~7300, with
// FETCH_SIZE 1.3GB of poll spam). Fix: each thread spins on only its 8B
// SENTINEL unit with s_sleep(1) wave backoff (quiet fabric => stores land
// fast), then loads the remaining 3 units once and tag-verifies (producer
// stored all 4 in the same wave/cycle; stragglers are rare retries).
//
// Structure (R3, proven): 256 blocks = 32 batch-groups (8 batches) x 8
// gate-slices (128 gate rows). Weights register-resident as bf16 MFMA
// B-fragments. h published as 8B single-copy-atomic units {2xbf16 h, tag=
// step} via relaxed AGENT-scope (sc0 sc1, MALL-coherent) stores; consumers
// poll tags directly - no fences, no flags, no producer drain. Parity-reuse
// safety: tag-t units are only overwritten at end of step t+1, which needs
// all peers' poll(t) complete. Tag poison 0xAAAAAAAA never equals live tags
// 1..1024 => no ws init. Dead-latch caps => wrong-answer-not-hang.

#define T_ 1024
#define I_ 64
#define H_ 256
#define NSLICE 8
#define NGROUP 32
#define MB 8      /* batches per group  */
#define HB 32     /* hidden units per block */
#define HROW 272  /* padded h_lds row (ushorts), 544 B = 34 x 16 B */

#define UNITS_PER_GROUP 1024                       /* 8B units per step */
#define UNITS_PER_PARITY (NGROUP * UNITS_PER_GROUP)
#define SENT_CAP (1 << 16)   /* sentinel dead-latch: ~64k sleep-sweeps */
#define VER_CAP (1 << 12)    /* verify dead-latch */

typedef float floatx4 __attribute__((ext_vector_type(4)));
typedef __bf16 bf16x8 __attribute__((ext_vector_type(8)));
typedef unsigned short ushortx8 __attribute__((ext_vector_type(8)));
typedef unsigned int uintx4 __attribute__((ext_vector_type(4)));
typedef unsigned int uint32;
typedef unsigned long long u64;

__device__ __forceinline__ float bf2f(uint32 u16) {
  uint32 u = u16 << 16;
  return __builtin_bit_cast(float, u);
}
__device__ __forceinline__ unsigned short f2bf(float f) {
  uint32 u = __builtin_bit_cast(uint32, f);
  u = (u + 0x7FFFu + ((u >> 16) & 1u)) >> 16;  // RNE
  return (unsigned short)u;
}
__device__ __forceinline__ bf16x8 packbf8(floatx4 a, floatx4 b) {
  bf16x8 r;
  r[0] = (__bf16)a[0]; r[1] = (__bf16)a[1];
  r[2] = (__bf16)a[2]; r[3] = (__bf16)a[3];
  r[4] = (__bf16)b[0]; r[5] = (__bf16)b[1];
  r[6] = (__bf16)b[2]; r[7] = (__bf16)b[3];
  return r;
}
__device__ __forceinline__ float fast_sig(float v) {
  return 1.0f / (1.0f + __expf(-v));
}
__device__ __forceinline__ float fast_tanh(float v) {
  float e = __expf(2.0f * v);
  return 1.0f - 2.0f / (e + 1.0f);
}
__device__ __forceinline__ u64 aload64(const u64* p) {
  return __hip_atomic_load(p, __ATOMIC_RELAXED, __HIP_MEMORY_SCOPE_AGENT);
}

__global__ __launch_bounds__(256, 1) void lstm_main(
    const float* __restrict__ x, const float* __restrict__ W_ih,
    const float* __restrict__ W_hh, const float* __restrict__ b_ih,
    const float* __restrict__ b_hh, u64* __restrict__ units) {
  const int tid = threadIdx.x;
  const int bid = blockIdx.x;
  const int s = bid >> 5;     // slice 0..7  (bid%8 == g%8 -> spread XCDs)
  const int g = bid & 31;     // group 0..31
  const int w = tid >> 6;     // wave id == gate type (i,f,g,o)
  const int lane = tid & 63;
  const int ln = lane & 15;   // MFMA n / A m
  const int lk = lane >> 4;   // MFMA k-subgroup (8 elems each)

  __shared__ float xch[4][2][16][8];                     // [gate][j][n][m]
  __shared__ __align__(16) unsigned short h_lds[MB][HROW];

  // zero h_lds (h_0 = 0 for t=0; also clears pad)
  {
    uint32* p = (uint32*)&h_lds[0][0];
    for (int i = tid; i < MB * HROW / 2; i += 256) p[i] = 0u;
  }

  // ---- preload weight B-fragments (bf16) + bias, once ----
  bf16x8 wf[2][10];
  float bias[2];
#pragma unroll
  for (int j = 0; j < 2; ++j) {
    const int row = w * 256 + s * HB + j * 16 + ln;
    bias[j] = b_ih[row] + b_hh[row];
#pragma unroll
    for (int kc = 0; kc < 10; ++kc) {
      const int kk = kc * 32 + lk * 8;
      const float* src = (kk < I_) ? (W_ih + (size_t)row * I_ + kk)
                                   : (W_hh + (size_t)row * H_ + (kk - I_));
      floatx4 f0 = *(const floatx4*)src;
      floatx4 f1 = *(const floatx4*)(src + 4);
      wf[j][kc] = packbf8(f0, f1);
    }
  }

  const int mb = ln & 7;                       // batch row (m>=8 duplicates)
  const float* xrow = x + ((size_t)(g * MB + mb)) * T_ * I_;
  // update-phase roles
  const int um = tid >> 5;                     // 0..7 batch
  const int uh = tid & 31;                     // 0..31 hidden local
  const int uj = uh >> 4, un = uh & 15;
  float c_reg = 0.0f;

  const size_t gbase = (size_t)g * UNITS_PER_GROUP;

  __syncthreads();

#pragma unroll 1
  for (int t = 0; t < T_; ++t) {
    // x loads issued first so they overlap the poll
    floatx4 xf0, xf1, xf2, xf3;
    {
      const float* src = xrow + t * I_ + lk * 8;
      xf0 = *(const floatx4*)(src);
      xf1 = *(const floatx4*)(src + 4);
      xf2 = *(const floatx4*)(src + 32);
      xf3 = *(const floatx4*)(src + 36);
    }

    if (t > 0) {
      const u64* up =
          units + (size_t)(t & 1) * UNITS_PER_PARITY + gbase + tid * 4;
      // ---- phase 1: QUIET sentinel poll (8B/thread, wave s_sleep backoff)
      u64 v0 = aload64(up + 0);
      bool pending = ((uint32)(v0 >> 32) != (uint32)t);
      int it = 0;
      while (__any(pending) && ++it < SENT_CAP) {
        __builtin_amdgcn_s_sleep(1);
        if (pending) {
          v0 = aload64(up + 0);
          pending = ((uint32)(v0 >> 32) != (uint32)t);
        }
      }
      // ---- phase 2: load remaining 3 units once, tag-verify (rare retry)
      u64 v1 = aload64(up + 1), v2 = aload64(up + 2), v3 = aload64(up + 3);
      bool ok = ((uint32)(v1 >> 32) == (uint32)t) &&
                ((uint32)(v2 >> 32) == (uint32)t) &&
                ((uint32)(v3 >> 32) == (uint32)t);
      int vt = 0;
      while (!__all(ok) && ++vt < VER_CAP) {
        __builtin_amdgcn_s_sleep(1);
        if (!ok) {
          v1 = aload64(up + 1);
          v2 = aload64(up + 2);
          v3 = aload64(up + 3);
          ok = ((uint32)(v1 >> 32) == (uint32)t) &&
               ((uint32)(v2 >> 32) == (uint32)t) &&
               ((uint32)(v3 >> 32) == (uint32)t);
        }
      }
      uintx4 d;
      d[0] = (uint32)v0; d[1] = (uint32)v1;
      d[2] = (uint32)v2; d[3] = (uint32)v3;
      // unit u = m*128 + dword; tid*4 = (tid>>5)*128 + (tid&31)*4
      uint32* dst = (uint32*)&h_lds[tid >> 5][0] + (tid & 31) * 4;
      *(uintx4*)dst = d;  // 16B aligned
    }
    __syncthreads();  // S1: h_lds ready

    bf16x8 af[10];
    af[0] = packbf8(xf0, xf1);
    af[1] = packbf8(xf2, xf3);
    const unsigned short* hrow = &h_lds[mb][0];
#pragma unroll
    for (int kc = 2; kc < 10; ++kc) {
      af[kc] =
          __builtin_bit_cast(bf16x8, *(const ushortx8*)(hrow + (kc - 2) * 32 +
                                                        lk * 8));
    }

    // ---- MFMA: D[m][n] = sum_k A[m][k] * W[n][k], bias in acc ----
    floatx4 acc[2];
    acc[0] = (floatx4){bias[0], bias[0], bias[0], bias[0]};
    acc[1] = (floatx4){bias[1], bias[1], bias[1], bias[1]};
#pragma unroll
    for (int kc = 0; kc < 10; ++kc) {
      acc[0] = __builtin_amdgcn_mfma_f32_16x16x32_bf16(af[kc], wf[0][kc],
                                                       acc[0], 0, 0, 0);
      acc[1] = __builtin_amdgcn_mfma_f32_16x16x32_bf16(af[kc], wf[1][kc],
                                                       acc[1], 0, 0, 0);
    }

    // ---- nonlinearity (wave-uniform branch) + LDS exchange ----
#pragma unroll
    for (int j = 0; j < 2; ++j) {
      floatx4 v = acc[j];
      if (w == 2) {
        v[0] = fast_tanh(v[0]); v[1] = fast_tanh(v[1]);
        v[2] = fast_tanh(v[2]); v[3] = fast_tanh(v[3]);
      } else {
        v[0] = fast_sig(v[0]); v[1] = fast_sig(v[1]);
        v[2] = fast_sig(v[2]); v[3] = fast_sig(v[3]);
      }
      if (lk < 2) {  // valid m rows 0..7 live in lanes 0..31, m = lk*4+reg
        *(floatx4*)&xch[w][j][ln][lk * 4] = v;
      }
    }
    __syncthreads();  // S2: gates ready

    // ---- c/h update: thread = (um, uh) ----
    float ig = xch[0][uj][un][um];
    float fg = xch[1][uj][un][um];
    float gg = xch[2][uj][un][um];
    float og = xch[3][uj][un][um];
    c_reg = fg * c_reg + ig * gg;
    float hv = og * fast_tanh(c_reg);

    // pair-pack via shfl, publish 8B unit {h pair, tag t+1}
    unsigned short hb = __builtin_bit_cast(unsigned short, (__bf16)hv);
    int pv = __shfl_xor((int)hb, 1);
    if ((uh & 1) == 0) {
      uint32 dword = (uint32)hb | ((uint32)(unsigned short)pv << 16);
      u64 val = (u64)dword | ((u64)(uint32)(t + 1) << 32);
      u64* dst = units + (size_t)((t + 1) & 1) * UNITS_PER_PARITY + gbase +
                 (um * 128 + s * 16 + (uh >> 1));
      __hip_atomic_store(dst, val, __ATOMIC_RELAXED,
                         __HIP_MEMORY_SCOPE_AGENT);
    }
  }
}

// out[b] = dot(h_T[b], fc_w) + fc_b. Final h = tag-1024 units in parity 0
// ((1023+1)&1 == 0). Bypass loads avoid stale cache lines across replays.
__global__ void lstm_fc(const u64* __restrict__ units,
                        const float* __restrict__ fc_w,
                        const float* __restrict__ fc_b,
                        float* __restrict__ out) {
  const int b = threadIdx.x;
  const int g = b >> 3, m = b & 7;
  const u64* base = units + (size_t)g * UNITS_PER_GROUP + m * 128;
  float sum = fc_b[0];
#pragma unroll 8
  for (int d = 0; d < 128; ++d) {
    u64 v = aload64(base + d);
    uint32 lo = (uint32)v;
    sum += bf2f(lo & 0xffffu) * fc_w[2 * d] + bf2f(lo >> 16) * fc_w[2 * d + 1];
  }
  out[b] = sum;
}

extern "C" void kernel_launch(void* const* d_in, const int* in_sizes, int n_in,
                              void* d_out, int out_size, void* d_ws,
                              size_t ws_size, hipStream_t stream) {
  const float* x    = (const float*)d_in[0];
  const float* W_ih = (const float*)d_in[1];
  const float* W_hh = (const float*)d_in[2];
  const float* b_ih = (const float*)d_in[3];
  const float* b_hh = (const float*)d_in[4];
  const float* fc_w = (const float*)d_in[5];
  const float* fc_b = (const float*)d_in[6];
  float* out = (float*)d_out;

  u64* units = (u64*)d_ws;  // 2 parities x 32 groups x 1024 units x 8B = 512KB
  // tag poison 0xAAAAAAAA != any live tag (1..1024) => no init needed.

  lstm_main<<<dim3(NGROUP * NSLICE), dim3(256), 0, stream>>>(
      x, W_ih, W_hh, b_ih, b_hh, units);
  lstm_fc<<<dim3(1), dim3(256), 0, stream>>>(units, fc_w, fc_b, out);
}